// Round 18
// baseline (263.195 us; speedup 1.0000x reference)
//
#include <hip/hip_runtime.h>
#include <hip/hip_bf16.h>

#define H 128
#define CAP 64          // bucket capacity per node (avg degree 16; P(deg>64) ~ 1e-20)
#define GBM 64
#define GBN 64
#define BW 128          // cols per sort bucket
#define BSH 7
#define BCAP 4096       // edges per sort bucket (avg 2048, max ~2300)
#define EPB 2048        // edges per binA block
#define RSHIFT 17       // row in bits [0,17), z in bits [17,27)
#define RMASK  0x1FFFF

typedef __attribute__((ext_vector_type(8))) short bf16x8;
typedef __attribute__((ext_vector_type(4))) float f32x4;
typedef unsigned long long u64;

__device__ __forceinline__ unsigned short f2b(float f) {
  __hip_bfloat16 h = __float2bfloat16(f);
  union { __hip_bfloat16 h; unsigned short u; } c; c.h = h; return c.u;
}
__device__ __forceinline__ float b2f(unsigned short u) {
  union { unsigned int i; float f; } c; c.i = (unsigned)u << 16; return c.f;
}

// ---------------- build: two-level counting sort by destination ----------------

__global__ __launch_bounds__(256) void k_binA(const int* __restrict__ row,
    const int* __restrict__ col, const float* __restrict__ ew,
    int* __restrict__ gcur, u64* __restrict__ binned, int E, int NB) {
  __shared__ int hist[1024];
  __shared__ int gbase[1024];
  int tid = threadIdx.x;
  for (int i = tid; i < NB; i += 256) hist[i] = 0;
  __syncthreads();
  int base = blockIdx.x * EPB;
  for (int j = tid; j < EPB; j += 256) {
    int e = base + j;
    if (e < E) atomicAdd(&hist[col[e] >> BSH], 1);
  }
  __syncthreads();
  for (int i = tid; i < NB; i += 256) {
    gbase[i] = atomicAdd(&gcur[i], hist[i]);
    hist[i] = 0;                               // reuse as local cursor
  }
  __syncthreads();
  for (int j = tid; j < EPB; j += 256) {
    int e = base + j;
    if (e < E) {
      int c = col[e];
      int b = c >> BSH;
      int r = atomicAdd(&hist[b], 1);
      int pos = gbase[b] + r;
      if (pos >= BCAP) pos = BCAP - 1;         // never expected (max bucket ~2300)
      unsigned pk = (unsigned)(c & (BW - 1)) | ((unsigned)row[e] << BSH);
      binned[(size_t)b * BCAP + pos] = (u64)pk | ((u64)(unsigned)__float_as_int(ew[e]) << 32);
    }
  }
}

// pass B: per bucket, per-col count + weight-sum (LDS); emit cnt and dinv only

__global__ __launch_bounds__(256) void k_binB(const int* __restrict__ gcur,
    const u64* __restrict__ binned, int* __restrict__ cnt, float* __restrict__ dinv, int n) {
  __shared__ int lcnt[BW];
  __shared__ float lws[BW];
  int b = blockIdx.x, tid = threadIdx.x;
  if (tid < BW) { lcnt[tid] = 0; lws[tid] = 0.f; }
  __syncthreads();
  int m = gcur[b];
  if (m > BCAP) m = BCAP;
  const u64* src = binned + (size_t)b * BCAP;
  for (int j = tid; j < m; j += 256) {
    u64 v = src[j];
    int cl = (int)(v & (BW - 1));
    atomicAdd(&lcnt[cl], 1);
    atomicAdd(&lws[cl], __int_as_float((int)(v >> 32)));
  }
  __syncthreads();
  if (tid < BW) {
    int c = b * BW + tid;
    if (c < n) {
      cnt[c] = min(lcnt[tid], CAP);
      dinv[c] = 1.f / sqrtf(1.f + lws[tid]);   // + self-loop weight
    }
  }
}

// pass C: write PACKED elist { row|z<<RSHIFT, norm=dinv[r]*w*dinv[c] }, pad to 16-multiple

__global__ __launch_bounds__(256) void k_binPack(const int* __restrict__ gcur,
    const u64* __restrict__ binned, int* __restrict__ cntp,
    const float* __restrict__ dinv, const int* __restrict__ z,
    int2* __restrict__ elist, int n) {
  __shared__ int lcur[BW];
  __shared__ float ldin[BW];
  int b = blockIdx.x, tid = threadIdx.x;
  if (tid < BW) {
    lcur[tid] = 0;
    int c = b * BW + tid;
    ldin[tid] = (c < n) ? dinv[c] : 0.f;
  }
  __syncthreads();
  int m = gcur[b];
  if (m > BCAP) m = BCAP;
  const u64* src = binned + (size_t)b * BCAP;
  for (int j = tid; j < m; j += 256) {
    u64 v = src[j];
    int cl = (int)(v & (BW - 1));
    int r = atomicAdd(&lcur[cl], 1);
    if (r < CAP) {
      int rw = (int)((v >> BSH) & RMASK);
      float w = __int_as_float((int)(v >> 32));
      float nrm = dinv[rw] * w * ldin[cl];
      int c = b * BW + cl;
      elist[(size_t)c * CAP + r] = make_int2(rw | (z[rw] << RSHIFT), __float_as_int(nrm));
    }
  }
  __syncthreads();
  if (tid < BW) {
    int c = b * BW + tid;
    if (c < n) {
      int mm = min(lcur[tid], CAP);
      int mp = (mm + 15) & ~15;
      if (mp > CAP) mp = CAP;
      cntp[c] = mp;
      for (int j = mm; j < mp; ++j)
        elist[(size_t)c * CAP + j] = make_int2(0, 0);   // zero-weight pad
    }
  }
}

// W1 -> transposed bf16 hi/lo: whl[0][n][k], whl[1][n][k]
__global__ void k_wprep(const float* __restrict__ W, unsigned short* __restrict__ whl) {
  int i = blockIdx.x * 256 + threadIdx.x;
  if (i >= H * H) return;
  int k = i >> 7, n = i & 127;
  float w = W[i];
  unsigned short hi = f2b(w);
  whl[n * H + k] = hi;
  whl[H * H + n * H + k] = f2b(w - b2f(hi));
}

// ---------------- need-set construction (head reads only 1000 nodes) ----------------

__global__ __launch_bounds__(256) void k_mark(const int* __restrict__ batch, int n,
    int* __restrict__ clist, const int2* __restrict__ elist, const int* __restrict__ cnt,
    unsigned int* __restrict__ bitmap, int nc) {
  int widx = (blockIdx.x * 256 + threadIdx.x) >> 6;
  if (widx >= nc) return;
  int lane = threadIdx.x & 63;
  int g = widx >> 1;
  int lo = 0, hi = n;
  while (lo < hi) { int mid = (lo + hi) >> 1; if (batch[mid] < g) lo = mid + 1; else hi = mid; }
  int v = lo + (widx & 1);
  if (lane == 0) {
    clist[widx] = v;
    atomicOr(&bitmap[v >> 5], 1u << (v & 31));
  }
  int m = min(cnt[v], CAP);
  if (lane < m) {
    int r = elist[(size_t)v * CAP + lane].x & RMASK;
    atomicOr(&bitmap[r >> 5], 1u << (r & 31));
  }
}

__global__ void k_compact(const unsigned int* __restrict__ bitmap,
                          int* __restrict__ slist, int* __restrict__ scount, int n) {
  int i = blockIdx.x * 256 + threadIdx.x;
  if (i >= n) return;
  if (bitmap[i >> 5] & (1u << (i & 31))) slist[atomicAdd(scount, 1)] = i;
}

// ---------------- VALU GEMM (small matrices): Y = X @ W (+bias, relu), fp32/bf16 out ----------------

#define FMA4(A, xs, wv) { A[0] = fmaf(xs, wv.x, A[0]); A[1] = fmaf(xs, wv.y, A[1]); \
                          A[2] = fmaf(xs, wv.z, A[2]); A[3] = fmaf(xs, wv.w, A[3]); }

__global__ __launch_bounds__(256, 2) void k_gemm(const float* __restrict__ X,
    const float* __restrict__ Wg, void* __restrict__ Yv, int Nrows,
    const float* __restrict__ bias, int relu, int outbf) {
  __shared__ float Ws[H][GBN + 4];
  int tid = threadIdx.x;
  int bm = blockIdx.x * GBM;
  int bn = blockIdx.y * GBN;
  for (int i = tid; i < H * (GBN / 4); i += 256) {
    int k = i >> 4, c4 = (i & 15) * 4;
    *(float4*)&Ws[k][c4] = *(const float4*)(Wg + k * H + bn + c4);
  }
  __syncthreads();
  int rg = tid >> 4, cg = tid & 15;
  int cg4 = cg * 4;
  int g0 = bm + rg * 4 + 0, g1 = g0 + 1, g2 = g0 + 2, g3 = g0 + 3;
  const float* xp0; const float* xp1; const float* xp2; const float* xp3;
  {
    int c0 = g0 < Nrows ? g0 : Nrows - 1;
    int c1 = g1 < Nrows ? g1 : Nrows - 1;
    int c2 = g2 < Nrows ? g2 : Nrows - 1;
    int c3 = g3 < Nrows ? g3 : Nrows - 1;
    xp0 = X + (size_t)c0 * H; xp1 = X + (size_t)c1 * H;
    xp2 = X + (size_t)c2 * H; xp3 = X + (size_t)c3 * H;
  }
  float a0[4] = {0,0,0,0}, a1[4] = {0,0,0,0}, a2[4] = {0,0,0,0}, a3[4] = {0,0,0,0};
  #pragma unroll 2
  for (int k = 0; k < H; k += 4) {
    float4 x0 = *(const float4*)(xp0 + k);
    float4 x1 = *(const float4*)(xp1 + k);
    float4 x2 = *(const float4*)(xp2 + k);
    float4 x3 = *(const float4*)(xp3 + k);
    float4 w0 = *(const float4*)&Ws[k + 0][cg4];
    float4 w1 = *(const float4*)&Ws[k + 1][cg4];
    float4 w2 = *(const float4*)&Ws[k + 2][cg4];
    float4 w3 = *(const float4*)&Ws[k + 3][cg4];
    FMA4(a0, x0.x, w0) FMA4(a0, x0.y, w1) FMA4(a0, x0.z, w2) FMA4(a0, x0.w, w3)
    FMA4(a1, x1.x, w0) FMA4(a1, x1.y, w1) FMA4(a1, x1.z, w2) FMA4(a1, x1.w, w3)
    FMA4(a2, x2.x, w0) FMA4(a2, x2.y, w1) FMA4(a2, x2.z, w2) FMA4(a2, x2.w, w3)
    FMA4(a3, x3.x, w0) FMA4(a3, x3.y, w1) FMA4(a3, x3.z, w2) FMA4(a3, x3.w, w3)
  }
  if (bias) {
    float4 bb = *(const float4*)(bias + bn + cg4);
    #pragma unroll
    for (int u = 0; u < 4; ++u) {
      a0[u] += ((const float*)&bb)[u]; a1[u] += ((const float*)&bb)[u];
      a2[u] += ((const float*)&bb)[u]; a3[u] += ((const float*)&bb)[u];
    }
  }
  if (relu) {
    #pragma unroll
    for (int u = 0; u < 4; ++u) {
      a0[u] = fmaxf(a0[u], 0.f); a1[u] = fmaxf(a1[u], 0.f);
      a2[u] = fmaxf(a2[u], 0.f); a3[u] = fmaxf(a3[u], 0.f);
    }
  }
  if (outbf) {
    unsigned short* Yb = (unsigned short*)Yv;
    ushort4 h0 = make_ushort4(f2b(a0[0]), f2b(a0[1]), f2b(a0[2]), f2b(a0[3]));
    ushort4 h1 = make_ushort4(f2b(a1[0]), f2b(a1[1]), f2b(a1[2]), f2b(a1[3]));
    ushort4 h2 = make_ushort4(f2b(a2[0]), f2b(a2[1]), f2b(a2[2]), f2b(a2[3]));
    ushort4 h3 = make_ushort4(f2b(a3[0]), f2b(a3[1]), f2b(a3[2]), f2b(a3[3]));
    if (g0 < Nrows) *(ushort4*)(Yb + (size_t)g0 * H + bn + cg4) = h0;
    if (g1 < Nrows) *(ushort4*)(Yb + (size_t)g1 * H + bn + cg4) = h1;
    if (g2 < Nrows) *(ushort4*)(Yb + (size_t)g2 * H + bn + cg4) = h2;
    if (g3 < Nrows) *(ushort4*)(Yb + (size_t)g3 * H + bn + cg4) = h3;
  } else {
    float* Y = (float*)Yv;
    if (g0 < Nrows) *(float4*)(Y + (size_t)g0 * H + bn + cg4) = make_float4(a0[0], a0[1], a0[2], a0[3]);
    if (g1 < Nrows) *(float4*)(Y + (size_t)g1 * H + bn + cg4) = make_float4(a1[0], a1[1], a1[2], a1[3]);
    if (g2 < Nrows) *(float4*)(Y + (size_t)g2 * H + bn + cg4) = make_float4(a2[0], a2[1], a2[2], a2[3]);
    if (g3 < Nrows) *(float4*)(Y + (size_t)g3 * H + bn + cg4) = make_float4(a3[0], a3[1], a3[2], a3[3]);
  }
}

// ---------------- MFMA GEMM: Yb = Xb @ (Whi + Wlo), persistent blocks, W staged once ----------------

#define MFMA_GRID 512   // 2 blocks/CU at 64KB LDS: stage W once, loop M-tiles

__global__ __launch_bounds__(256, 2) void k_gemm_mfma(const unsigned short* __restrict__ Xb,
    const unsigned short* __restrict__ WHL, unsigned short* __restrict__ Yb, int Nrows) {
  __shared__ unsigned short WsH[H * H];
  __shared__ unsigned short WsL[H * H];
  int tid = threadIdx.x;
  {
    const int4* src = (const int4*)WHL;          // 2 * 2048 int4
    int4* dH = (int4*)WsH;
    int4* dL = (int4*)WsL;
    for (int i = tid; i < 2048; i += 256) {
      dH[i] = src[i];
      dL[i] = src[2048 + i];
    }
  }
  __syncthreads();
  int lane = tid & 63, wave = tid >> 6;
  int mrow = lane & 15, h = lane >> 4;
  int ntile = (Nrows + 63) >> 6;
  for (int t = blockIdx.x; t < ntile; t += MFMA_GRID) {
    int Mbase = t * 64 + wave * 16;
    int arow = Mbase + mrow;
    if (arow >= Nrows) arow = Nrows - 1;         // clamp reads; stores predicated
    const unsigned short* xr = Xb + (size_t)arow * H;
    bf16x8 a[4];
    #pragma unroll
    for (int kt = 0; kt < 4; ++kt)
      a[kt] = *(const bf16x8*)(xr + kt * 32 + h * 8);
    f32x4 acc[8];
    #pragma unroll
    for (int nt = 0; nt < 8; ++nt) acc[nt] = (f32x4){0.f, 0.f, 0.f, 0.f};
    #pragma unroll
    for (int nt = 0; nt < 8; ++nt) {
      #pragma unroll
      for (int kt = 0; kt < 4; ++kt) {
        int boff = (nt * 16 + mrow) * H + kt * 32 + h * 8;
        bf16x8 bh = *(const bf16x8*)(WsH + boff);
        bf16x8 bl = *(const bf16x8*)(WsL + boff);
        acc[nt] = __builtin_amdgcn_mfma_f32_16x16x32_bf16(a[kt], bh, acc[nt], 0, 0, 0);
        acc[nt] = __builtin_amdgcn_mfma_f32_16x16x32_bf16(a[kt], bl, acc[nt], 0, 0, 0);
      }
    }
    #pragma unroll
    for (int nt = 0; nt < 8; ++nt) {
      int ocol = nt * 16 + mrow;
      #pragma unroll
      for (int r = 0; r < 4; ++r) {
        int orow = Mbase + 4 * h + r;
        if (orow < Nrows) Yb[(size_t)orow * H + ocol] = f2b(acc[nt][r]);
      }
    }
  }
}

// ---------------- Aggregation (bf16 rows) over node LIST — 16-deep, no predication ----------------

__global__ __launch_bounds__(256) void k_aggb_list(const unsigned short* __restrict__ XWB,
    const int2* __restrict__ elist, const int* __restrict__ cntp,
    const float* __restrict__ dinv, const float* __restrict__ bias,
    float* __restrict__ out, const int* __restrict__ slist,
    const int* __restrict__ scount, int relu) {
  int widx = (blockIdx.x * 256 + threadIdx.x) >> 5;   // one node per 32-lane half
  if (widx >= *scount) return;
  int wid = slist[widx];
  int c4 = threadIdx.x & 31;
  const ushort4* xw4 = (const ushort4*)XWB;
  int m = cntp[wid];                                  // padded to multiple of 16
  const int2* ep = elist + (size_t)wid * CAP;
  float dc = dinv[wid];
  float d2 = dc * dc;
  ushort4 s = xw4[(size_t)wid * 32 + c4];
  float4 acc = make_float4(d2 * b2f(s.x), d2 * b2f(s.y), d2 * b2f(s.z), d2 * b2f(s.w));
  for (int j0 = 0; j0 < m; j0 += 16) {
    int2 Ee[16];
    #pragma unroll
    for (int u = 0; u < 16; ++u) Ee[u] = ep[j0 + u];
    ushort4 V[16];
    #pragma unroll
    for (int u = 0; u < 16; ++u) V[u] = xw4[(size_t)(Ee[u].x & RMASK) * 32 + c4];
    #pragma unroll
    for (int u = 0; u < 16; ++u) {
      float nn = __int_as_float(Ee[u].y);
      acc.x = fmaf(nn, b2f(V[u].x), acc.x);
      acc.y = fmaf(nn, b2f(V[u].y), acc.y);
      acc.z = fmaf(nn, b2f(V[u].z), acc.z);
      acc.w = fmaf(nn, b2f(V[u].w), acc.w);
    }
  }
  float4 bb = ((const float4*)bias)[c4];
  acc.x += bb.x; acc.y += bb.y; acc.z += bb.z; acc.w += bb.w;
  if (relu) {
    acc.x = fmaxf(acc.x, 0.f); acc.y = fmaxf(acc.y, 0.f);
    acc.z = fmaxf(acc.z, 0.f); acc.w = fmaxf(acc.w, 0.f);
  }
  ((float4*)out)[(size_t)wid * 32 + c4] = acc;
}

// ---------------- Layer-2: aggregate fp32 h2 at centers — 16-deep ----------------

#define EFMA(nn, vv) { acc.x = fmaf(nn, vv.x, acc.x); acc.y = fmaf(nn, vv.y, acc.y); \
                       acc.z = fmaf(nn, vv.z, acc.z); acc.w = fmaf(nn, vv.w, acc.w); }

__global__ __launch_bounds__(256) void k_agg_last(const float* __restrict__ X,
    const int2* __restrict__ elist, const int* __restrict__ cntp,
    const float* __restrict__ dinv, const int* __restrict__ clist,
    float* __restrict__ out, int nc) {
  int widx = (blockIdx.x * 256 + threadIdx.x) >> 5;
  if (widx >= nc) return;
  int v = clist[widx];
  int c4 = threadIdx.x & 31;
  const float4* x4 = (const float4*)X;
  int m = cntp[v];
  const int2* ep = elist + (size_t)v * CAP;
  float dc = dinv[v];
  float d2 = dc * dc;
  float4 s = x4[(size_t)v * 32 + c4];
  float4 acc = make_float4(d2 * s.x, d2 * s.y, d2 * s.z, d2 * s.w);
  for (int j0 = 0; j0 < m; j0 += 16) {
    int2 Ee[16];
    #pragma unroll
    for (int u = 0; u < 16; ++u) Ee[u] = ep[j0 + u];
    float4 V[16];
    #pragma unroll
    for (int u = 0; u < 16; ++u) V[u] = x4[(size_t)(Ee[u].x & RMASK) * 32 + c4];
    #pragma unroll
    for (int u = 0; u < 16; ++u) {
      float nn = __int_as_float(Ee[u].y);
      EFMA(nn, V[u])
    }
  }
  ((float4*)out)[(size_t)widx * 32 + c4] = acc;
}

// ---------------- Layer-0: aggregate projected embeddings (bf16 ztw) — 16-deep ----------------

__global__ __launch_bounds__(256) void k_agg_emb(const unsigned short* __restrict__ ZTW,
    const int* __restrict__ z, const int2* __restrict__ elist, const int* __restrict__ cntp,
    const float* __restrict__ dinv, const float* __restrict__ bias,
    unsigned short* __restrict__ out, int n) {
  int wid = (blockIdx.x * 256 + threadIdx.x) >> 5;    // one node per 32-lane half
  if (wid >= n) return;
  int c4 = threadIdx.x & 31;
  const ushort4* zt4 = (const ushort4*)ZTW;           // row = 32 ushort4 (256B)
  int m = cntp[wid];
  const int2* ep = elist + (size_t)wid * CAP;
  float dc = dinv[wid];
  float d2 = dc * dc;
  ushort4 s = zt4[(size_t)z[wid] * 32 + c4];
  float4 acc = make_float4(d2 * b2f(s.x), d2 * b2f(s.y), d2 * b2f(s.z), d2 * b2f(s.w));
  for (int j0 = 0; j0 < m; j0 += 16) {
    int2 Ee[16];
    #pragma unroll
    for (int u = 0; u < 16; ++u) Ee[u] = ep[j0 + u];
    ushort4 V[16];
    #pragma unroll
    for (int u = 0; u < 16; ++u) V[u] = zt4[(size_t)((unsigned)Ee[u].x >> RSHIFT) * 32 + c4];
    #pragma unroll
    for (int u = 0; u < 16; ++u) {
      float nn = __int_as_float(Ee[u].y);
      acc.x = fmaf(nn, b2f(V[u].x), acc.x);
      acc.y = fmaf(nn, b2f(V[u].y), acc.y);
      acc.z = fmaf(nn, b2f(V[u].z), acc.z);
      acc.w = fmaf(nn, b2f(V[u].w), acc.w);
    }
  }
  float4 bb = ((const float4*)bias)[c4];
  ushort4 o = make_ushort4(f2b(fmaxf(acc.x + bb.x, 0.f)),
                           f2b(fmaxf(acc.y + bb.y, 0.f)),
                           f2b(fmaxf(acc.z + bb.z, 0.f)),
                           f2b(fmaxf(acc.w + bb.w, 0.f)));
  ((ushort4*)out)[(size_t)wid * 32 + c4] = o;
}

// ---------------- Head (y rows already ordered: 2g, 2g+1) ----------------

__global__ __launch_bounds__(128) void k_head_y(const float* __restrict__ Y,
    const float* __restrict__ W1, const float* __restrict__ b1,
    const float* __restrict__ W2, const float* __restrict__ b2,
    float* __restrict__ out, int G) {
  int g = blockIdx.x, t = threadIdx.x;
  __shared__ float hs[H];
  hs[t] = Y[(size_t)(2 * g) * H + t] * Y[(size_t)(2 * g + 1) * H + t];
  __syncthreads();
  float a = b1[t];
  #pragma unroll 8
  for (int k = 0; k < H; ++k) a = fmaf(hs[k], W1[k * H + t], a);
  a = fmaxf(a, 0.f);
  a *= W2[t];
  for (int off = 32; off > 0; off >>= 1) a += __shfl_down(a, off);
  __shared__ float wsum[2];
  if ((t & 63) == 0) wsum[t >> 6] = a;
  __syncthreads();
  if (t == 0) out[g] = wsum[0] + wsum[1] + b2[0];
}

// ---------------- launch ----------------

extern "C" void kernel_launch(void* const* d_in, const int* in_sizes, int n_in,
                              void* d_out, int out_size, void* d_ws, size_t ws_size,
                              hipStream_t stream) {
  const int* z     = (const int*)d_in[0];
  const int* eidx  = (const int*)d_in[1];
  const int* batch = (const int*)d_in[2];
  const float* ew  = (const float*)d_in[3];
  const float* ztab= (const float*)d_in[4];
  const float *W0, *W1, *W2, *b0, *b1, *b2, *l1W, *l1b, *l2W, *l2b;
  if (n_in >= 15) {
    W0 = (const float*)d_in[5];  W1 = (const float*)d_in[6];  W2 = (const float*)d_in[7];
    b0 = (const float*)d_in[8];  b1 = (const float*)d_in[9];  b2 = (const float*)d_in[10];
    l1W = (const float*)d_in[11]; l1b = (const float*)d_in[12];
    l2W = (const float*)d_in[13]; l2b = (const float*)d_in[14];
  } else {
    const float* Wss = (const float*)d_in[5];
    W0 = Wss; W1 = Wss + H * H; W2 = Wss + 2 * H * H;
    const float* bs = (const float*)d_in[6];
    b0 = bs; b1 = bs + H; b2 = bs + 2 * H;
    l1W = (const float*)d_in[7]; l1b = (const float*)d_in[8];
    l2W = (const float*)d_in[9]; l2b = (const float*)d_in[10];
  }
  int N = in_sizes[0];
  int E = in_sizes[3];
  int ZTOT = in_sizes[4];      // MAXZ * H
  int MAXZ = ZTOT / H;
  int G = out_size;
  float* fout = (float*)d_out;
  int NC = 2 * G;              // center nodes (pairs)
  int MAXS = NC * (CAP + 1);   // worst-case |S2|
  int NB = (N + BW - 1) >> BSH;  // sort buckets (<=1024)

  size_t woff = 0;
  auto alloc = [&](size_t bytes) {
    void* p = (char*)d_ws + woff;
    woff += (bytes + 255) & ~(size_t)255;
    return p;
  };
  unsigned short* h1b   = (unsigned short*)alloc((size_t)N * H * 2);  // h1 bf16
  unsigned short* xwb   = (unsigned short*)alloc((size_t)N * H * 2);  // h1 @ W1 bf16
  float*          bufB  = (float*)alloc((size_t)N * H * 4);           // h2 (S2 rows)
  unsigned int*   bitmap= (unsigned int*)alloc(((size_t)N + 31) / 32 * 4);
  int*            scount= (int*)alloc(4);
  int*            gcur  = (int*)alloc((size_t)NB * 4);                // contiguous w/ bitmap: one memset
  float*          dinv  = (float*)alloc((size_t)N * 4);
  int*            cnt   = (int*)alloc((size_t)N * 4);
  int*            cntp  = (int*)alloc((size_t)N * 4);
  unsigned short* ztw   = (unsigned short*)alloc((size_t)ZTOT * 2);   // ztab @ W0, bf16
  unsigned short* whl   = (unsigned short*)alloc((size_t)2 * H * H * 2); // W1^T hi/lo bf16
  int*            clist = (int*)alloc((size_t)NC * 4);
  int*            slist = (int*)alloc((size_t)MAXS * 4);
  float*          agg2  = (float*)alloc((size_t)NC * H * 4);
  float*          ybuf  = (float*)alloc((size_t)NC * H * 4);
  u64*            binned= (u64*)alloc((size_t)NB * BCAP * 8);
  int2*           elist = (int2*)alloc((size_t)N * CAP * 8);

  const int* erow = eidx;
  const int* ecol = eidx + E;

  // zero bitmap + scount + gcur in one shot (contiguous allocs)
  size_t zlen = ((((size_t)N + 31) / 32 * 4 + 255) & ~(size_t)255) + 256
              + (((size_t)NB * 4 + 255) & ~(size_t)255);
  hipMemsetAsync(bitmap, 0, zlen, stream);

  int nb = (N + 255) / 256;
  int hgrid = (N + 7) / 8;        // half-per-node kernels

  k_binA<<<(E + EPB - 1) / EPB, 256, 0, stream>>>(erow, ecol, ew, gcur, binned, E, NB);
  k_binB<<<NB, 256, 0, stream>>>(gcur, binned, cnt, dinv, N);
  k_binPack<<<NB, 256, 0, stream>>>(gcur, binned, cntp, dinv, z, elist, N);
  // project z-table through W0 once (1000 rows), bf16 out
  dim3 zgrid((MAXZ + GBM - 1) / GBM, H / GBN);
  k_gemm<<<zgrid, 256, 0, stream>>>(ztab, W0, ztw, MAXZ, nullptr, 0, 1);
  k_wprep<<<(H * H + 255) / 256, 256, 0, stream>>>(W1, whl);
  k_mark<<<(NC + 3) / 4, 256, 0, stream>>>(batch, N, clist, elist, cnt, bitmap, NC);
  k_compact<<<nb, 256, 0, stream>>>(bitmap, slist, scount, N);

  // layer 0: h1 = relu(Agg(ztw[z]) + b0) -> bf16   (one node per 32-lane half)
  k_agg_emb<<<hgrid, 256, 0, stream>>>(ztw, z, elist, cntp, dinv, b0, h1b, N);
  // layer 1: MFMA GEMM (persistent blocks, bf16 X, LDS-staged hi/lo W1) -> bf16; aggregate ONLY S2 nodes
  k_gemm_mfma<<<MFMA_GRID, 256, 0, stream>>>(h1b, whl, xwb, N);
  k_aggb_list<<<(MAXS + 7) / 8, 256, 0, stream>>>(xwb, elist, cntp, dinv, b1, bufB, slist, scount, 1);
  // layer 2 (aggregate-first): t = A.h2 at 1000 centers; y = t @ W2 + b2
  k_agg_last<<<(NC + 7) / 8, 256, 0, stream>>>(bufB, elist, cntp, dinv, clist, agg2, NC);
  dim3 ygrid((NC + GBM - 1) / GBM, H / GBN);
  k_gemm<<<ygrid, 256, 0, stream>>>(agg2, W2, ybuf, NC, b2, 0, 0);

  k_head_y<<<G, 128, 0, stream>>>(ybuf, l1W, l1b, l2W, l2b, fout, G);
}

// Round 19
// 250.088 us; speedup vs baseline: 1.0524x; 1.0524x over previous
//
#include <hip/hip_runtime.h>
#include <hip/hip_bf16.h>

#define H 128
#define CAP 64          // bucket capacity per node (avg degree 16; P(deg>64) ~ 1e-20)
#define GBM 64
#define GBN 64
#define BW 128          // cols per sort bucket
#define BSH 7
#define BCAP 4096       // edges per sort bucket (avg 2048, max ~2300)
#define EPB 2048        // edges per binA block
#define RSHIFT 17       // row in bits [0,17), z in bits [17,27)
#define RMASK  0x1FFFF

typedef __attribute__((ext_vector_type(8))) short bf16x8;
typedef __attribute__((ext_vector_type(4))) float f32x4;
typedef unsigned long long u64;

__device__ __forceinline__ unsigned short f2b(float f) {
  __hip_bfloat16 h = __float2bfloat16(f);
  union { __hip_bfloat16 h; unsigned short u; } c; c.h = h; return c.u;
}
__device__ __forceinline__ float b2f(unsigned short u) {
  union { unsigned int i; float f; } c; c.i = (unsigned)u << 16; return c.f;
}

// ---------------- build: two-level counting sort by destination ----------------

__global__ __launch_bounds__(256) void k_binA(const int* __restrict__ row,
    const int* __restrict__ col, const float* __restrict__ ew,
    int* __restrict__ gcur, u64* __restrict__ binned, int E, int NB) {
  __shared__ int hist[1024];
  __shared__ int gbase[1024];
  int tid = threadIdx.x;
  for (int i = tid; i < NB; i += 256) hist[i] = 0;
  __syncthreads();
  int base = blockIdx.x * EPB;
  for (int j = tid; j < EPB; j += 256) {
    int e = base + j;
    if (e < E) atomicAdd(&hist[col[e] >> BSH], 1);
  }
  __syncthreads();
  for (int i = tid; i < NB; i += 256) {
    gbase[i] = atomicAdd(&gcur[i], hist[i]);
    hist[i] = 0;                               // reuse as local cursor
  }
  __syncthreads();
  for (int j = tid; j < EPB; j += 256) {
    int e = base + j;
    if (e < E) {
      int c = col[e];
      int b = c >> BSH;
      int r = atomicAdd(&hist[b], 1);
      int pos = gbase[b] + r;
      if (pos >= BCAP) pos = BCAP - 1;         // never expected (max bucket ~2300)
      unsigned pk = (unsigned)(c & (BW - 1)) | ((unsigned)row[e] << BSH);
      binned[(size_t)b * BCAP + pos] = (u64)pk | ((u64)(unsigned)__float_as_int(ew[e]) << 32);
    }
  }
}

// pass B: per bucket, per-col count + weight-sum (LDS); emit cnt and dinv only

__global__ __launch_bounds__(256) void k_binB(const int* __restrict__ gcur,
    const u64* __restrict__ binned, int* __restrict__ cnt, float* __restrict__ dinv, int n) {
  __shared__ int lcnt[BW];
  __shared__ float lws[BW];
  int b = blockIdx.x, tid = threadIdx.x;
  if (tid < BW) { lcnt[tid] = 0; lws[tid] = 0.f; }
  __syncthreads();
  int m = gcur[b];
  if (m > BCAP) m = BCAP;
  const u64* src = binned + (size_t)b * BCAP;
  for (int j = tid; j < m; j += 256) {
    u64 v = src[j];
    int cl = (int)(v & (BW - 1));
    atomicAdd(&lcnt[cl], 1);
    atomicAdd(&lws[cl], __int_as_float((int)(v >> 32)));
  }
  __syncthreads();
  if (tid < BW) {
    int c = b * BW + tid;
    if (c < n) {
      cnt[c] = min(lcnt[tid], CAP);
      dinv[c] = 1.f / sqrtf(1.f + lws[tid]);   // + self-loop weight
    }
  }
}

// pass C: write PACKED elist { row|z<<RSHIFT, norm=dinv[r]*w*dinv[c] }, pad to 8-multiple

__global__ __launch_bounds__(256) void k_binPack(const int* __restrict__ gcur,
    const u64* __restrict__ binned, int* __restrict__ cntp,
    const float* __restrict__ dinv, const int* __restrict__ z,
    int2* __restrict__ elist, int n) {
  __shared__ int lcur[BW];
  __shared__ float ldin[BW];
  int b = blockIdx.x, tid = threadIdx.x;
  if (tid < BW) {
    lcur[tid] = 0;
    int c = b * BW + tid;
    ldin[tid] = (c < n) ? dinv[c] : 0.f;
  }
  __syncthreads();
  int m = gcur[b];
  if (m > BCAP) m = BCAP;
  const u64* src = binned + (size_t)b * BCAP;
  for (int j = tid; j < m; j += 256) {
    u64 v = src[j];
    int cl = (int)(v & (BW - 1));
    int r = atomicAdd(&lcur[cl], 1);
    if (r < CAP) {
      int rw = (int)((v >> BSH) & RMASK);
      float w = __int_as_float((int)(v >> 32));
      float nrm = dinv[rw] * w * ldin[cl];
      int c = b * BW + cl;
      elist[(size_t)c * CAP + r] = make_int2(rw | (z[rw] << RSHIFT), __float_as_int(nrm));
    }
  }
  __syncthreads();
  if (tid < BW) {
    int c = b * BW + tid;
    if (c < n) {
      int mm = min(lcur[tid], CAP);
      int mp = (mm + 7) & ~7;
      if (mp > CAP) mp = CAP;
      cntp[c] = mp;
      for (int j = mm; j < mp; ++j)
        elist[(size_t)c * CAP + j] = make_int2(0, 0);   // zero-weight pad
    }
  }
}

// W1 -> transposed bf16 hi/lo: whl[0][n][k], whl[1][n][k]
__global__ void k_wprep(const float* __restrict__ W, unsigned short* __restrict__ whl) {
  int i = blockIdx.x * 256 + threadIdx.x;
  if (i >= H * H) return;
  int k = i >> 7, n = i & 127;
  float w = W[i];
  unsigned short hi = f2b(w);
  whl[n * H + k] = hi;
  whl[H * H + n * H + k] = f2b(w - b2f(hi));
}

// ---------------- need-set construction (head reads only 1000 nodes) ----------------

__global__ __launch_bounds__(256) void k_mark(const int* __restrict__ batch, int n,
    int* __restrict__ clist, const int2* __restrict__ elist, const int* __restrict__ cnt,
    unsigned int* __restrict__ bitmap, int nc) {
  int widx = (blockIdx.x * 256 + threadIdx.x) >> 6;
  if (widx >= nc) return;
  int lane = threadIdx.x & 63;
  int g = widx >> 1;
  int lo = 0, hi = n;
  while (lo < hi) { int mid = (lo + hi) >> 1; if (batch[mid] < g) lo = mid + 1; else hi = mid; }
  int v = lo + (widx & 1);
  if (lane == 0) {
    clist[widx] = v;
    atomicOr(&bitmap[v >> 5], 1u << (v & 31));
  }
  int m = min(cnt[v], CAP);
  if (lane < m) {
    int r = elist[(size_t)v * CAP + lane].x & RMASK;
    atomicOr(&bitmap[r >> 5], 1u << (r & 31));
  }
}

__global__ void k_compact(const unsigned int* __restrict__ bitmap,
                          int* __restrict__ slist, int* __restrict__ scount, int n) {
  int i = blockIdx.x * 256 + threadIdx.x;
  if (i >= n) return;
  if (bitmap[i >> 5] & (1u << (i & 31))) slist[atomicAdd(scount, 1)] = i;
}

// ---------------- VALU GEMM (small matrices): Y = X @ W (+bias, relu), fp32/bf16 out ----------------

#define FMA4(A, xs, wv) { A[0] = fmaf(xs, wv.x, A[0]); A[1] = fmaf(xs, wv.y, A[1]); \
                          A[2] = fmaf(xs, wv.z, A[2]); A[3] = fmaf(xs, wv.w, A[3]); }

__global__ __launch_bounds__(256, 2) void k_gemm(const float* __restrict__ X,
    const float* __restrict__ Wg, void* __restrict__ Yv, int Nrows,
    const float* __restrict__ bias, int relu, int outbf) {
  __shared__ float Ws[H][GBN + 4];
  int tid = threadIdx.x;
  int bm = blockIdx.x * GBM;
  int bn = blockIdx.y * GBN;
  for (int i = tid; i < H * (GBN / 4); i += 256) {
    int k = i >> 4, c4 = (i & 15) * 4;
    *(float4*)&Ws[k][c4] = *(const float4*)(Wg + k * H + bn + c4);
  }
  __syncthreads();
  int rg = tid >> 4, cg = tid & 15;
  int cg4 = cg * 4;
  int g0 = bm + rg * 4 + 0, g1 = g0 + 1, g2 = g0 + 2, g3 = g0 + 3;
  const float* xp0; const float* xp1; const float* xp2; const float* xp3;
  {
    int c0 = g0 < Nrows ? g0 : Nrows - 1;
    int c1 = g1 < Nrows ? g1 : Nrows - 1;
    int c2 = g2 < Nrows ? g2 : Nrows - 1;
    int c3 = g3 < Nrows ? g3 : Nrows - 1;
    xp0 = X + (size_t)c0 * H; xp1 = X + (size_t)c1 * H;
    xp2 = X + (size_t)c2 * H; xp3 = X + (size_t)c3 * H;
  }
  float a0[4] = {0,0,0,0}, a1[4] = {0,0,0,0}, a2[4] = {0,0,0,0}, a3[4] = {0,0,0,0};
  #pragma unroll 2
  for (int k = 0; k < H; k += 4) {
    float4 x0 = *(const float4*)(xp0 + k);
    float4 x1 = *(const float4*)(xp1 + k);
    float4 x2 = *(const float4*)(xp2 + k);
    float4 x3 = *(const float4*)(xp3 + k);
    float4 w0 = *(const float4*)&Ws[k + 0][cg4];
    float4 w1 = *(const float4*)&Ws[k + 1][cg4];
    float4 w2 = *(const float4*)&Ws[k + 2][cg4];
    float4 w3 = *(const float4*)&Ws[k + 3][cg4];
    FMA4(a0, x0.x, w0) FMA4(a0, x0.y, w1) FMA4(a0, x0.z, w2) FMA4(a0, x0.w, w3)
    FMA4(a1, x1.x, w0) FMA4(a1, x1.y, w1) FMA4(a1, x1.z, w2) FMA4(a1, x1.w, w3)
    FMA4(a2, x2.x, w0) FMA4(a2, x2.y, w1) FMA4(a2, x2.z, w2) FMA4(a2, x2.w, w3)
    FMA4(a3, x3.x, w0) FMA4(a3, x3.y, w1) FMA4(a3, x3.z, w2) FMA4(a3, x3.w, w3)
  }
  if (bias) {
    float4 bb = *(const float4*)(bias + bn + cg4);
    #pragma unroll
    for (int u = 0; u < 4; ++u) {
      a0[u] += ((const float*)&bb)[u]; a1[u] += ((const float*)&bb)[u];
      a2[u] += ((const float*)&bb)[u]; a3[u] += ((const float*)&bb)[u];
    }
  }
  if (relu) {
    #pragma unroll
    for (int u = 0; u < 4; ++u) {
      a0[u] = fmaxf(a0[u], 0.f); a1[u] = fmaxf(a1[u], 0.f);
      a2[u] = fmaxf(a2[u], 0.f); a3[u] = fmaxf(a3[u], 0.f);
    }
  }
  if (outbf) {
    unsigned short* Yb = (unsigned short*)Yv;
    ushort4 h0 = make_ushort4(f2b(a0[0]), f2b(a0[1]), f2b(a0[2]), f2b(a0[3]));
    ushort4 h1 = make_ushort4(f2b(a1[0]), f2b(a1[1]), f2b(a1[2]), f2b(a1[3]));
    ushort4 h2 = make_ushort4(f2b(a2[0]), f2b(a2[1]), f2b(a2[2]), f2b(a2[3]));
    ushort4 h3 = make_ushort4(f2b(a3[0]), f2b(a3[1]), f2b(a3[2]), f2b(a3[3]));
    if (g0 < Nrows) *(ushort4*)(Yb + (size_t)g0 * H + bn + cg4) = h0;
    if (g1 < Nrows) *(ushort4*)(Yb + (size_t)g1 * H + bn + cg4) = h1;
    if (g2 < Nrows) *(ushort4*)(Yb + (size_t)g2 * H + bn + cg4) = h2;
    if (g3 < Nrows) *(ushort4*)(Yb + (size_t)g3 * H + bn + cg4) = h3;
  } else {
    float* Y = (float*)Yv;
    if (g0 < Nrows) *(float4*)(Y + (size_t)g0 * H + bn + cg4) = make_float4(a0[0], a0[1], a0[2], a0[3]);
    if (g1 < Nrows) *(float4*)(Y + (size_t)g1 * H + bn + cg4) = make_float4(a1[0], a1[1], a1[2], a1[3]);
    if (g2 < Nrows) *(float4*)(Y + (size_t)g2 * H + bn + cg4) = make_float4(a2[0], a2[1], a2[2], a2[3]);
    if (g3 < Nrows) *(float4*)(Y + (size_t)g3 * H + bn + cg4) = make_float4(a3[0], a3[1], a3[2], a3[3]);
  }
}

// ---------------- MFMA GEMM: Yb = Xb @ (Whi + Wlo), persistent blocks, W staged once ----------------

#define MFMA_GRID 512   // 2 blocks/CU at 64KB LDS: stage W once, loop M-tiles

__global__ __launch_bounds__(256, 2) void k_gemm_mfma(const unsigned short* __restrict__ Xb,
    const unsigned short* __restrict__ WHL, unsigned short* __restrict__ Yb, int Nrows) {
  __shared__ unsigned short WsH[H * H];
  __shared__ unsigned short WsL[H * H];
  int tid = threadIdx.x;
  {
    const int4* src = (const int4*)WHL;          // 2 * 2048 int4
    int4* dH = (int4*)WsH;
    int4* dL = (int4*)WsL;
    for (int i = tid; i < 2048; i += 256) {
      dH[i] = src[i];
      dL[i] = src[2048 + i];
    }
  }
  __syncthreads();
  int lane = tid & 63, wave = tid >> 6;
  int mrow = lane & 15, h = lane >> 4;
  int ntile = (Nrows + 63) >> 6;
  for (int t = blockIdx.x; t < ntile; t += MFMA_GRID) {
    int Mbase = t * 64 + wave * 16;
    int arow = Mbase + mrow;
    if (arow >= Nrows) arow = Nrows - 1;         // clamp reads; stores predicated
    const unsigned short* xr = Xb + (size_t)arow * H;
    bf16x8 a[4];
    #pragma unroll
    for (int kt = 0; kt < 4; ++kt)
      a[kt] = *(const bf16x8*)(xr + kt * 32 + h * 8);
    f32x4 acc[8];
    #pragma unroll
    for (int nt = 0; nt < 8; ++nt) acc[nt] = (f32x4){0.f, 0.f, 0.f, 0.f};
    #pragma unroll
    for (int nt = 0; nt < 8; ++nt) {
      #pragma unroll
      for (int kt = 0; kt < 4; ++kt) {
        int boff = (nt * 16 + mrow) * H + kt * 32 + h * 8;
        bf16x8 bh = *(const bf16x8*)(WsH + boff);
        bf16x8 bl = *(const bf16x8*)(WsL + boff);
        acc[nt] = __builtin_amdgcn_mfma_f32_16x16x32_bf16(a[kt], bh, acc[nt], 0, 0, 0);
        acc[nt] = __builtin_amdgcn_mfma_f32_16x16x32_bf16(a[kt], bl, acc[nt], 0, 0, 0);
      }
    }
    #pragma unroll
    for (int nt = 0; nt < 8; ++nt) {
      int ocol = nt * 16 + mrow;
      #pragma unroll
      for (int r = 0; r < 4; ++r) {
        int orow = Mbase + 4 * h + r;
        if (orow < Nrows) Yb[(size_t)orow * H + ocol] = f2b(acc[nt][r]);
      }
    }
  }
}

// ---------------- Aggregation (bf16 rows) over node LIST — 8-deep, no predication ----------------

__global__ __launch_bounds__(256) void k_aggb_list(const unsigned short* __restrict__ XWB,
    const int2* __restrict__ elist, const int* __restrict__ cntp,
    const float* __restrict__ dinv, const float* __restrict__ bias,
    float* __restrict__ out, const int* __restrict__ slist,
    const int* __restrict__ scount, int relu) {
  int widx = (blockIdx.x * 256 + threadIdx.x) >> 5;   // one node per 32-lane half
  if (widx >= *scount) return;
  int wid = slist[widx];
  int c4 = threadIdx.x & 31;
  const ushort4* xw4 = (const ushort4*)XWB;
  int m = cntp[wid];                                  // padded to multiple of 8
  const int2* ep = elist + (size_t)wid * CAP;
  float dc = dinv[wid];
  float d2 = dc * dc;
  ushort4 s = xw4[(size_t)wid * 32 + c4];
  float4 acc = make_float4(d2 * b2f(s.x), d2 * b2f(s.y), d2 * b2f(s.z), d2 * b2f(s.w));
  for (int j0 = 0; j0 < m; j0 += 8) {
    int2 Ee[8];
    #pragma unroll
    for (int u = 0; u < 8; ++u) Ee[u] = ep[j0 + u];
    ushort4 V[8];
    #pragma unroll
    for (int u = 0; u < 8; ++u) V[u] = xw4[(size_t)(Ee[u].x & RMASK) * 32 + c4];
    #pragma unroll
    for (int u = 0; u < 8; ++u) {
      float nn = __int_as_float(Ee[u].y);
      acc.x = fmaf(nn, b2f(V[u].x), acc.x);
      acc.y = fmaf(nn, b2f(V[u].y), acc.y);
      acc.z = fmaf(nn, b2f(V[u].z), acc.z);
      acc.w = fmaf(nn, b2f(V[u].w), acc.w);
    }
  }
  float4 bb = ((const float4*)bias)[c4];
  acc.x += bb.x; acc.y += bb.y; acc.z += bb.z; acc.w += bb.w;
  if (relu) {
    acc.x = fmaxf(acc.x, 0.f); acc.y = fmaxf(acc.y, 0.f);
    acc.z = fmaxf(acc.z, 0.f); acc.w = fmaxf(acc.w, 0.f);
  }
  ((float4*)out)[(size_t)wid * 32 + c4] = acc;
}

// ---------------- Layer-2: aggregate fp32 h2 at centers — 8-deep ----------------

#define EFMA(nn, vv) { acc.x = fmaf(nn, vv.x, acc.x); acc.y = fmaf(nn, vv.y, acc.y); \
                       acc.z = fmaf(nn, vv.z, acc.z); acc.w = fmaf(nn, vv.w, acc.w); }

__global__ __launch_bounds__(256) void k_agg_last(const float* __restrict__ X,
    const int2* __restrict__ elist, const int* __restrict__ cntp,
    const float* __restrict__ dinv, const int* __restrict__ clist,
    float* __restrict__ out, int nc) {
  int widx = (blockIdx.x * 256 + threadIdx.x) >> 5;
  if (widx >= nc) return;
  int v = clist[widx];
  int c4 = threadIdx.x & 31;
  const float4* x4 = (const float4*)X;
  int m = cntp[v];
  const int2* ep = elist + (size_t)v * CAP;
  float dc = dinv[v];
  float d2 = dc * dc;
  float4 s = x4[(size_t)v * 32 + c4];
  float4 acc = make_float4(d2 * s.x, d2 * s.y, d2 * s.z, d2 * s.w);
  for (int j0 = 0; j0 < m; j0 += 8) {
    int2 Ee[8];
    #pragma unroll
    for (int u = 0; u < 8; ++u) Ee[u] = ep[j0 + u];
    float4 V[8];
    #pragma unroll
    for (int u = 0; u < 8; ++u) V[u] = x4[(size_t)(Ee[u].x & RMASK) * 32 + c4];
    #pragma unroll
    for (int u = 0; u < 8; ++u) {
      float nn = __int_as_float(Ee[u].y);
      EFMA(nn, V[u])
    }
  }
  ((float4*)out)[(size_t)widx * 32 + c4] = acc;
}

// ---------------- Layer-0: aggregate projected embeddings (bf16 ztw) — 8-deep ----------------

__global__ __launch_bounds__(256) void k_agg_emb(const unsigned short* __restrict__ ZTW,
    const int* __restrict__ z, const int2* __restrict__ elist, const int* __restrict__ cntp,
    const float* __restrict__ dinv, const float* __restrict__ bias,
    unsigned short* __restrict__ out, int n) {
  int wid = (blockIdx.x * 256 + threadIdx.x) >> 5;    // one node per 32-lane half
  if (wid >= n) return;
  int c4 = threadIdx.x & 31;
  const ushort4* zt4 = (const ushort4*)ZTW;           // row = 32 ushort4 (256B)
  int m = cntp[wid];
  const int2* ep = elist + (size_t)wid * CAP;
  float dc = dinv[wid];
  float d2 = dc * dc;
  ushort4 s = zt4[(size_t)z[wid] * 32 + c4];
  float4 acc = make_float4(d2 * b2f(s.x), d2 * b2f(s.y), d2 * b2f(s.z), d2 * b2f(s.w));
  for (int j0 = 0; j0 < m; j0 += 8) {
    int2 Ee[8];
    #pragma unroll
    for (int u = 0; u < 8; ++u) Ee[u] = ep[j0 + u];
    ushort4 V[8];
    #pragma unroll
    for (int u = 0; u < 8; ++u) V[u] = zt4[(size_t)((unsigned)Ee[u].x >> RSHIFT) * 32 + c4];
    #pragma unroll
    for (int u = 0; u < 8; ++u) {
      float nn = __int_as_float(Ee[u].y);
      acc.x = fmaf(nn, b2f(V[u].x), acc.x);
      acc.y = fmaf(nn, b2f(V[u].y), acc.y);
      acc.z = fmaf(nn, b2f(V[u].z), acc.z);
      acc.w = fmaf(nn, b2f(V[u].w), acc.w);
    }
  }
  float4 bb = ((const float4*)bias)[c4];
  ushort4 o = make_ushort4(f2b(fmaxf(acc.x + bb.x, 0.f)),
                           f2b(fmaxf(acc.y + bb.y, 0.f)),
                           f2b(fmaxf(acc.z + bb.z, 0.f)),
                           f2b(fmaxf(acc.w + bb.w, 0.f)));
  ((ushort4*)out)[(size_t)wid * 32 + c4] = o;
}

// ---------------- Head (y rows already ordered: 2g, 2g+1) ----------------

__global__ __launch_bounds__(128) void k_head_y(const float* __restrict__ Y,
    const float* __restrict__ W1, const float* __restrict__ b1,
    const float* __restrict__ W2, const float* __restrict__ b2,
    float* __restrict__ out, int G) {
  int g = blockIdx.x, t = threadIdx.x;
  __shared__ float hs[H];
  hs[t] = Y[(size_t)(2 * g) * H + t] * Y[(size_t)(2 * g + 1) * H + t];
  __syncthreads();
  float a = b1[t];
  #pragma unroll 8
  for (int k = 0; k < H; ++k) a = fmaf(hs[k], W1[k * H + t], a);
  a = fmaxf(a, 0.f);
  a *= W2[t];
  for (int off = 32; off > 0; off >>= 1) a += __shfl_down(a, off);
  __shared__ float wsum[2];
  if ((t & 63) == 0) wsum[t >> 6] = a;
  __syncthreads();
  if (t == 0) out[g] = wsum[0] + wsum[1] + b2[0];
}

// ---------------- launch ----------------

extern "C" void kernel_launch(void* const* d_in, const int* in_sizes, int n_in,
                              void* d_out, int out_size, void* d_ws, size_t ws_size,
                              hipStream_t stream) {
  const int* z     = (const int*)d_in[0];
  const int* eidx  = (const int*)d_in[1];
  const int* batch = (const int*)d_in[2];
  const float* ew  = (const float*)d_in[3];
  const float* ztab= (const float*)d_in[4];
  const float *W0, *W1, *W2, *b0, *b1, *b2, *l1W, *l1b, *l2W, *l2b;
  if (n_in >= 15) {
    W0 = (const float*)d_in[5];  W1 = (const float*)d_in[6];  W2 = (const float*)d_in[7];
    b0 = (const float*)d_in[8];  b1 = (const float*)d_in[9];  b2 = (const float*)d_in[10];
    l1W = (const float*)d_in[11]; l1b = (const float*)d_in[12];
    l2W = (const float*)d_in[13]; l2b = (const float*)d_in[14];
  } else {
    const float* Wss = (const float*)d_in[5];
    W0 = Wss; W1 = Wss + H * H; W2 = Wss + 2 * H * H;
    const float* bs = (const float*)d_in[6];
    b0 = bs; b1 = bs + H; b2 = bs + 2 * H;
    l1W = (const float*)d_in[7]; l1b = (const float*)d_in[8];
    l2W = (const float*)d_in[9]; l2b = (const float*)d_in[10];
  }
  int N = in_sizes[0];
  int E = in_sizes[3];
  int ZTOT = in_sizes[4];      // MAXZ * H
  int MAXZ = ZTOT / H;
  int G = out_size;
  float* fout = (float*)d_out;
  int NC = 2 * G;              // center nodes (pairs)
  int MAXS = NC * (CAP + 1);   // worst-case |S2|
  int NB = (N + BW - 1) >> BSH;  // sort buckets (<=1024)

  size_t woff = 0;
  auto alloc = [&](size_t bytes) {
    void* p = (char*)d_ws + woff;
    woff += (bytes + 255) & ~(size_t)255;
    return p;
  };
  unsigned short* h1b   = (unsigned short*)alloc((size_t)N * H * 2);  // h1 bf16
  unsigned short* xwb   = (unsigned short*)alloc((size_t)N * H * 2);  // h1 @ W1 bf16
  float*          bufB  = (float*)alloc((size_t)N * H * 4);           // h2 (S2 rows)
  unsigned int*   bitmap= (unsigned int*)alloc(((size_t)N + 31) / 32 * 4);
  int*            scount= (int*)alloc(4);
  int*            gcur  = (int*)alloc((size_t)NB * 4);                // contiguous w/ bitmap: one memset
  float*          dinv  = (float*)alloc((size_t)N * 4);
  int*            cnt   = (int*)alloc((size_t)N * 4);
  int*            cntp  = (int*)alloc((size_t)N * 4);
  unsigned short* ztw   = (unsigned short*)alloc((size_t)ZTOT * 2);   // ztab @ W0, bf16
  unsigned short* whl   = (unsigned short*)alloc((size_t)2 * H * H * 2); // W1^T hi/lo bf16
  int*            clist = (int*)alloc((size_t)NC * 4);
  int*            slist = (int*)alloc((size_t)MAXS * 4);
  float*          agg2  = (float*)alloc((size_t)NC * H * 4);
  float*          ybuf  = (float*)alloc((size_t)NC * H * 4);
  u64*            binned= (u64*)alloc((size_t)NB * BCAP * 8);
  int2*           elist = (int2*)alloc((size_t)N * CAP * 8);

  const int* erow = eidx;
  const int* ecol = eidx + E;

  // zero bitmap + scount + gcur in one shot (contiguous allocs)
  size_t zlen = ((((size_t)N + 31) / 32 * 4 + 255) & ~(size_t)255) + 256
              + (((size_t)NB * 4 + 255) & ~(size_t)255);
  hipMemsetAsync(bitmap, 0, zlen, stream);

  int nb = (N + 255) / 256;
  int hgrid = (N + 7) / 8;        // half-per-node kernels

  k_binA<<<(E + EPB - 1) / EPB, 256, 0, stream>>>(erow, ecol, ew, gcur, binned, E, NB);
  k_binB<<<NB, 256, 0, stream>>>(gcur, binned, cnt, dinv, N);
  k_binPack<<<NB, 256, 0, stream>>>(gcur, binned, cntp, dinv, z, elist, N);
  // project z-table through W0 once (1000 rows), bf16 out
  dim3 zgrid((MAXZ + GBM - 1) / GBM, H / GBN);
  k_gemm<<<zgrid, 256, 0, stream>>>(ztab, W0, ztw, MAXZ, nullptr, 0, 1);
  k_wprep<<<(H * H + 255) / 256, 256, 0, stream>>>(W1, whl);
  k_mark<<<(NC + 3) / 4, 256, 0, stream>>>(batch, N, clist, elist, cnt, bitmap, NC);
  k_compact<<<nb, 256, 0, stream>>>(bitmap, slist, scount, N);

  // layer 0: h1 = relu(Agg(ztw[z]) + b0) -> bf16   (one node per 32-lane half)
  k_agg_emb<<<hgrid, 256, 0, stream>>>(ztw, z, elist, cntp, dinv, b0, h1b, N);
  // layer 1: MFMA GEMM (persistent blocks, bf16 X, LDS-staged hi/lo W1) -> bf16; aggregate ONLY S2 nodes
  k_gemm_mfma<<<MFMA_GRID, 256, 0, stream>>>(h1b, whl, xwb, N);
  k_aggb_list<<<(MAXS + 7) / 8, 256, 0, stream>>>(xwb, elist, cntp, dinv, b1, bufB, slist, scount, 1);
  // layer 2 (aggregate-first): t = A.h2 at 1000 centers; y = t @ W2 + b2
  k_agg_last<<<(NC + 7) / 8, 256, 0, stream>>>(bufB, elist, cntp, dinv, clist, agg2, NC);
  dim3 ygrid((NC + GBM - 1) / GBM, H / GBN);
  k_gemm<<<ygrid, 256, 0, stream>>>(agg2, W2, ybuf, NC, b2, 0, 0);

  k_head_y<<<G, 128, 0, stream>>>(ybuf, l1W, l1b, l2W, l2b, fout, G);
}

// Round 20
// 243.352 us; speedup vs baseline: 1.0815x; 1.0277x over previous
//
#include <hip/hip_runtime.h>
#include <hip/hip_bf16.h>

#define H 128
#define CAP 64          // bucket capacity per node (avg degree 16; P(deg>64) ~ 1e-20)
#define GBM 64
#define GBN 64
#define BW 128          // cols per sort bucket
#define BSH 7
#define BCAP 4096       // edges per sort bucket (avg 2048, max ~2300)
#define EPB 2048        // edges per binA block
#define RSHIFT 17       // row in bits [0,17), z in bits [17,27)
#define RMASK  0x1FFFF

typedef __attribute__((ext_vector_type(8))) short bf16x8;
typedef __attribute__((ext_vector_type(4))) float f32x4;
typedef unsigned long long u64;

__device__ __forceinline__ unsigned short f2b(float f) {
  __hip_bfloat16 h = __float2bfloat16(f);
  union { __hip_bfloat16 h; unsigned short u; } c; c.h = h; return c.u;
}
__device__ __forceinline__ float b2f(unsigned short u) {
  union { unsigned int i; float f; } c; c.i = (unsigned)u << 16; return c.f;
}

// ---------------- build: two-level counting sort by destination (512-thread blocks) ----------------

__global__ __launch_bounds__(512) void k_binA(const int* __restrict__ row,
    const int* __restrict__ col, const float* __restrict__ ew,
    int* __restrict__ gcur, u64* __restrict__ binned, int E, int NB) {
  __shared__ int hist[1024];
  __shared__ int gbase[1024];
  int tid = threadIdx.x;
  for (int i = tid; i < NB; i += 512) hist[i] = 0;
  __syncthreads();
  int base = blockIdx.x * EPB;
  for (int j = tid; j < EPB; j += 512) {
    int e = base + j;
    if (e < E) atomicAdd(&hist[col[e] >> BSH], 1);
  }
  __syncthreads();
  for (int i = tid; i < NB; i += 512) {
    gbase[i] = atomicAdd(&gcur[i], hist[i]);
    hist[i] = 0;                               // reuse as local cursor
  }
  __syncthreads();
  for (int j = tid; j < EPB; j += 512) {
    int e = base + j;
    if (e < E) {
      int c = col[e];
      int b = c >> BSH;
      int r = atomicAdd(&hist[b], 1);
      int pos = gbase[b] + r;
      if (pos >= BCAP) pos = BCAP - 1;         // never expected (max bucket ~2300)
      unsigned pk = (unsigned)(c & (BW - 1)) | ((unsigned)row[e] << BSH);
      binned[(size_t)b * BCAP + pos] = (u64)pk | ((u64)(unsigned)__float_as_int(ew[e]) << 32);
    }
  }
}

// pass B: per bucket, per-col count + weight-sum (LDS); emit cnt and dinv only

__global__ __launch_bounds__(512) void k_binB(const int* __restrict__ gcur,
    const u64* __restrict__ binned, int* __restrict__ cnt, float* __restrict__ dinv, int n) {
  __shared__ int lcnt[BW];
  __shared__ float lws[BW];
  int b = blockIdx.x, tid = threadIdx.x;
  if (tid < BW) { lcnt[tid] = 0; lws[tid] = 0.f; }
  __syncthreads();
  int m = gcur[b];
  if (m > BCAP) m = BCAP;
  const u64* src = binned + (size_t)b * BCAP;
  for (int j = tid; j < m; j += 512) {
    u64 v = src[j];
    int cl = (int)(v & (BW - 1));
    atomicAdd(&lcnt[cl], 1);
    atomicAdd(&lws[cl], __int_as_float((int)(v >> 32)));
  }
  __syncthreads();
  if (tid < BW) {
    int c = b * BW + tid;
    if (c < n) {
      cnt[c] = min(lcnt[tid], CAP);
      dinv[c] = 1.f / sqrtf(1.f + lws[tid]);   // + self-loop weight
    }
  }
}

// pass C: write PACKED elist { row|z<<RSHIFT, norm=dinv[r]*w*dinv[c] }, pad to 8-multiple

__global__ __launch_bounds__(512) void k_binPack(const int* __restrict__ gcur,
    const u64* __restrict__ binned, int* __restrict__ cntp,
    const float* __restrict__ dinv, const int* __restrict__ z,
    int2* __restrict__ elist, int n) {
  __shared__ int lcur[BW];
  __shared__ float ldin[BW];
  int b = blockIdx.x, tid = threadIdx.x;
  if (tid < BW) {
    lcur[tid] = 0;
    int c = b * BW + tid;
    ldin[tid] = (c < n) ? dinv[c] : 0.f;
  }
  __syncthreads();
  int m = gcur[b];
  if (m > BCAP) m = BCAP;
  const u64* src = binned + (size_t)b * BCAP;
  for (int j = tid; j < m; j += 512) {
    u64 v = src[j];
    int cl = (int)(v & (BW - 1));
    int r = atomicAdd(&lcur[cl], 1);
    if (r < CAP) {
      int rw = (int)((v >> BSH) & RMASK);
      float w = __int_as_float((int)(v >> 32));
      float nrm = dinv[rw] * w * ldin[cl];
      int c = b * BW + cl;
      elist[(size_t)c * CAP + r] = make_int2(rw | (z[rw] << RSHIFT), __float_as_int(nrm));
    }
  }
  __syncthreads();
  if (tid < BW) {
    int c = b * BW + tid;
    if (c < n) {
      int mm = min(lcur[tid], CAP);
      int mp = (mm + 7) & ~7;
      if (mp > CAP) mp = CAP;
      cntp[c] = mp;
      for (int j = mm; j < mp; ++j)
        elist[(size_t)c * CAP + j] = make_int2(0, 0);   // zero-weight pad
    }
  }
}

// W1 -> transposed bf16 hi/lo: whl[0][n][k], whl[1][n][k]
__global__ void k_wprep(const float* __restrict__ W, unsigned short* __restrict__ whl) {
  int i = blockIdx.x * 256 + threadIdx.x;
  if (i >= H * H) return;
  int k = i >> 7, n = i & 127;
  float w = W[i];
  unsigned short hi = f2b(w);
  whl[n * H + k] = hi;
  whl[H * H + n * H + k] = f2b(w - b2f(hi));
}

// ---------------- need-set construction (head reads only 1000 nodes) ----------------

__global__ __launch_bounds__(256) void k_mark(const int* __restrict__ batch, int n,
    int* __restrict__ clist, const int2* __restrict__ elist, const int* __restrict__ cnt,
    unsigned int* __restrict__ bitmap, int nc) {
  int widx = (blockIdx.x * 256 + threadIdx.x) >> 6;
  if (widx >= nc) return;
  int lane = threadIdx.x & 63;
  int g = widx >> 1;
  int lo = 0, hi = n;
  while (lo < hi) { int mid = (lo + hi) >> 1; if (batch[mid] < g) lo = mid + 1; else hi = mid; }
  int v = lo + (widx & 1);
  if (lane == 0) {
    clist[widx] = v;
    atomicOr(&bitmap[v >> 5], 1u << (v & 31));
  }
  int m = min(cnt[v], CAP);
  if (lane < m) {
    int r = elist[(size_t)v * CAP + lane].x & RMASK;
    atomicOr(&bitmap[r >> 5], 1u << (r & 31));
  }
}

__global__ void k_compact(const unsigned int* __restrict__ bitmap,
                          int* __restrict__ slist, int* __restrict__ scount, int n) {
  int i = blockIdx.x * 256 + threadIdx.x;
  if (i >= n) return;
  if (bitmap[i >> 5] & (1u << (i & 31))) slist[atomicAdd(scount, 1)] = i;
}

// ---------------- VALU GEMM (small matrices): Y = X @ W (+bias, relu), fp32/bf16 out ----------------

#define FMA4(A, xs, wv) { A[0] = fmaf(xs, wv.x, A[0]); A[1] = fmaf(xs, wv.y, A[1]); \
                          A[2] = fmaf(xs, wv.z, A[2]); A[3] = fmaf(xs, wv.w, A[3]); }

__global__ __launch_bounds__(256, 2) void k_gemm(const float* __restrict__ X,
    const float* __restrict__ Wg, void* __restrict__ Yv, int Nrows,
    const float* __restrict__ bias, int relu, int outbf) {
  __shared__ float Ws[H][GBN + 4];
  int tid = threadIdx.x;
  int bm = blockIdx.x * GBM;
  int bn = blockIdx.y * GBN;
  for (int i = tid; i < H * (GBN / 4); i += 256) {
    int k = i >> 4, c4 = (i & 15) * 4;
    *(float4*)&Ws[k][c4] = *(const float4*)(Wg + k * H + bn + c4);
  }
  __syncthreads();
  int rg = tid >> 4, cg = tid & 15;
  int cg4 = cg * 4;
  int g0 = bm + rg * 4 + 0, g1 = g0 + 1, g2 = g0 + 2, g3 = g0 + 3;
  const float* xp0; const float* xp1; const float* xp2; const float* xp3;
  {
    int c0 = g0 < Nrows ? g0 : Nrows - 1;
    int c1 = g1 < Nrows ? g1 : Nrows - 1;
    int c2 = g2 < Nrows ? g2 : Nrows - 1;
    int c3 = g3 < Nrows ? g3 : Nrows - 1;
    xp0 = X + (size_t)c0 * H; xp1 = X + (size_t)c1 * H;
    xp2 = X + (size_t)c2 * H; xp3 = X + (size_t)c3 * H;
  }
  float a0[4] = {0,0,0,0}, a1[4] = {0,0,0,0}, a2[4] = {0,0,0,0}, a3[4] = {0,0,0,0};
  #pragma unroll 2
  for (int k = 0; k < H; k += 4) {
    float4 x0 = *(const float4*)(xp0 + k);
    float4 x1 = *(const float4*)(xp1 + k);
    float4 x2 = *(const float4*)(xp2 + k);
    float4 x3 = *(const float4*)(xp3 + k);
    float4 w0 = *(const float4*)&Ws[k + 0][cg4];
    float4 w1 = *(const float4*)&Ws[k + 1][cg4];
    float4 w2 = *(const float4*)&Ws[k + 2][cg4];
    float4 w3 = *(const float4*)&Ws[k + 3][cg4];
    FMA4(a0, x0.x, w0) FMA4(a0, x0.y, w1) FMA4(a0, x0.z, w2) FMA4(a0, x0.w, w3)
    FMA4(a1, x1.x, w0) FMA4(a1, x1.y, w1) FMA4(a1, x1.z, w2) FMA4(a1, x1.w, w3)
    FMA4(a2, x2.x, w0) FMA4(a2, x2.y, w1) FMA4(a2, x2.z, w2) FMA4(a2, x2.w, w3)
    FMA4(a3, x3.x, w0) FMA4(a3, x3.y, w1) FMA4(a3, x3.z, w2) FMA4(a3, x3.w, w3)
  }
  if (bias) {
    float4 bb = *(const float4*)(bias + bn + cg4);
    #pragma unroll
    for (int u = 0; u < 4; ++u) {
      a0[u] += ((const float*)&bb)[u]; a1[u] += ((const float*)&bb)[u];
      a2[u] += ((const float*)&bb)[u]; a3[u] += ((const float*)&bb)[u];
    }
  }
  if (relu) {
    #pragma unroll
    for (int u = 0; u < 4; ++u) {
      a0[u] = fmaxf(a0[u], 0.f); a1[u] = fmaxf(a1[u], 0.f);
      a2[u] = fmaxf(a2[u], 0.f); a3[u] = fmaxf(a3[u], 0.f);
    }
  }
  if (outbf) {
    unsigned short* Yb = (unsigned short*)Yv;
    ushort4 h0 = make_ushort4(f2b(a0[0]), f2b(a0[1]), f2b(a0[2]), f2b(a0[3]));
    ushort4 h1 = make_ushort4(f2b(a1[0]), f2b(a1[1]), f2b(a1[2]), f2b(a1[3]));
    ushort4 h2 = make_ushort4(f2b(a2[0]), f2b(a2[1]), f2b(a2[2]), f2b(a2[3]));
    ushort4 h3 = make_ushort4(f2b(a3[0]), f2b(a3[1]), f2b(a3[2]), f2b(a3[3]));
    if (g0 < Nrows) *(ushort4*)(Yb + (size_t)g0 * H + bn + cg4) = h0;
    if (g1 < Nrows) *(ushort4*)(Yb + (size_t)g1 * H + bn + cg4) = h1;
    if (g2 < Nrows) *(ushort4*)(Yb + (size_t)g2 * H + bn + cg4) = h2;
    if (g3 < Nrows) *(ushort4*)(Yb + (size_t)g3 * H + bn + cg4) = h3;
  } else {
    float* Y = (float*)Yv;
    if (g0 < Nrows) *(float4*)(Y + (size_t)g0 * H + bn + cg4) = make_float4(a0[0], a0[1], a0[2], a0[3]);
    if (g1 < Nrows) *(float4*)(Y + (size_t)g1 * H + bn + cg4) = make_float4(a1[0], a1[1], a1[2], a1[3]);
    if (g2 < Nrows) *(float4*)(Y + (size_t)g2 * H + bn + cg4) = make_float4(a2[0], a2[1], a2[2], a2[3]);
    if (g3 < Nrows) *(float4*)(Y + (size_t)g3 * H + bn + cg4) = make_float4(a3[0], a3[1], a3[2], a3[3]);
  }
}

// ---------------- MFMA GEMM: Yb = Xb @ (Whi + Wlo), persistent blocks, W staged once ----------------

#define MFMA_GRID 512   // 2 blocks/CU at 64KB LDS: stage W once, loop M-tiles

__global__ __launch_bounds__(256, 2) void k_gemm_mfma(const unsigned short* __restrict__ Xb,
    const unsigned short* __restrict__ WHL, unsigned short* __restrict__ Yb, int Nrows) {
  __shared__ unsigned short WsH[H * H];
  __shared__ unsigned short WsL[H * H];
  int tid = threadIdx.x;
  {
    const int4* src = (const int4*)WHL;          // 2 * 2048 int4
    int4* dH = (int4*)WsH;
    int4* dL = (int4*)WsL;
    for (int i = tid; i < 2048; i += 256) {
      dH[i] = src[i];
      dL[i] = src[2048 + i];
    }
  }
  __syncthreads();
  int lane = tid & 63, wave = tid >> 6;
  int mrow = lane & 15, h = lane >> 4;
  int ntile = (Nrows + 63) >> 6;
  for (int t = blockIdx.x; t < ntile; t += MFMA_GRID) {
    int Mbase = t * 64 + wave * 16;
    int arow = Mbase + mrow;
    if (arow >= Nrows) arow = Nrows - 1;         // clamp reads; stores predicated
    const unsigned short* xr = Xb + (size_t)arow * H;
    bf16x8 a[4];
    #pragma unroll
    for (int kt = 0; kt < 4; ++kt)
      a[kt] = *(const bf16x8*)(xr + kt * 32 + h * 8);
    f32x4 acc[8];
    #pragma unroll
    for (int nt = 0; nt < 8; ++nt) acc[nt] = (f32x4){0.f, 0.f, 0.f, 0.f};
    #pragma unroll
    for (int nt = 0; nt < 8; ++nt) {
      #pragma unroll
      for (int kt = 0; kt < 4; ++kt) {
        int boff = (nt * 16 + mrow) * H + kt * 32 + h * 8;
        bf16x8 bh = *(const bf16x8*)(WsH + boff);
        bf16x8 bl = *(const bf16x8*)(WsL + boff);
        acc[nt] = __builtin_amdgcn_mfma_f32_16x16x32_bf16(a[kt], bh, acc[nt], 0, 0, 0);
        acc[nt] = __builtin_amdgcn_mfma_f32_16x16x32_bf16(a[kt], bl, acc[nt], 0, 0, 0);
      }
    }
    #pragma unroll
    for (int nt = 0; nt < 8; ++nt) {
      int ocol = nt * 16 + mrow;
      #pragma unroll
      for (int r = 0; r < 4; ++r) {
        int orow = Mbase + 4 * h + r;
        if (orow < Nrows) Yb[(size_t)orow * H + ocol] = f2b(acc[nt][r]);
      }
    }
  }
}

// ---------------- Aggregation (bf16 rows) over node LIST — 8-deep, no predication ----------------

__global__ __launch_bounds__(256) void k_aggb_list(const unsigned short* __restrict__ XWB,
    const int2* __restrict__ elist, const int* __restrict__ cntp,
    const float* __restrict__ dinv, const float* __restrict__ bias,
    float* __restrict__ out, const int* __restrict__ slist,
    const int* __restrict__ scount, int relu) {
  int widx = (blockIdx.x * 256 + threadIdx.x) >> 5;   // one node per 32-lane half
  if (widx >= *scount) return;
  int wid = slist[widx];
  int c4 = threadIdx.x & 31;
  const ushort4* xw4 = (const ushort4*)XWB;
  int m = cntp[wid];                                  // padded to multiple of 8
  const int2* ep = elist + (size_t)wid * CAP;
  float dc = dinv[wid];
  float d2 = dc * dc;
  ushort4 s = xw4[(size_t)wid * 32 + c4];
  float4 acc = make_float4(d2 * b2f(s.x), d2 * b2f(s.y), d2 * b2f(s.z), d2 * b2f(s.w));
  for (int j0 = 0; j0 < m; j0 += 8) {
    int2 Ee[8];
    #pragma unroll
    for (int u = 0; u < 8; ++u) Ee[u] = ep[j0 + u];
    ushort4 V[8];
    #pragma unroll
    for (int u = 0; u < 8; ++u) V[u] = xw4[(size_t)(Ee[u].x & RMASK) * 32 + c4];
    #pragma unroll
    for (int u = 0; u < 8; ++u) {
      float nn = __int_as_float(Ee[u].y);
      acc.x = fmaf(nn, b2f(V[u].x), acc.x);
      acc.y = fmaf(nn, b2f(V[u].y), acc.y);
      acc.z = fmaf(nn, b2f(V[u].z), acc.z);
      acc.w = fmaf(nn, b2f(V[u].w), acc.w);
    }
  }
  float4 bb = ((const float4*)bias)[c4];
  acc.x += bb.x; acc.y += bb.y; acc.z += bb.z; acc.w += bb.w;
  if (relu) {
    acc.x = fmaxf(acc.x, 0.f); acc.y = fmaxf(acc.y, 0.f);
    acc.z = fmaxf(acc.z, 0.f); acc.w = fmaxf(acc.w, 0.f);
  }
  ((float4*)out)[(size_t)wid * 32 + c4] = acc;
}

// ---------------- Layer-2: aggregate fp32 h2 at centers — 8-deep ----------------

#define EFMA(nn, vv) { acc.x = fmaf(nn, vv.x, acc.x); acc.y = fmaf(nn, vv.y, acc.y); \
                       acc.z = fmaf(nn, vv.z, acc.z); acc.w = fmaf(nn, vv.w, acc.w); }

__global__ __launch_bounds__(256) void k_agg_last(const float* __restrict__ X,
    const int2* __restrict__ elist, const int* __restrict__ cntp,
    const float* __restrict__ dinv, const int* __restrict__ clist,
    float* __restrict__ out, int nc) {
  int widx = (blockIdx.x * 256 + threadIdx.x) >> 5;
  if (widx >= nc) return;
  int v = clist[widx];
  int c4 = threadIdx.x & 31;
  const float4* x4 = (const float4*)X;
  int m = cntp[v];
  const int2* ep = elist + (size_t)v * CAP;
  float dc = dinv[v];
  float d2 = dc * dc;
  float4 s = x4[(size_t)v * 32 + c4];
  float4 acc = make_float4(d2 * s.x, d2 * s.y, d2 * s.z, d2 * s.w);
  for (int j0 = 0; j0 < m; j0 += 8) {
    int2 Ee[8];
    #pragma unroll
    for (int u = 0; u < 8; ++u) Ee[u] = ep[j0 + u];
    float4 V[8];
    #pragma unroll
    for (int u = 0; u < 8; ++u) V[u] = x4[(size_t)(Ee[u].x & RMASK) * 32 + c4];
    #pragma unroll
    for (int u = 0; u < 8; ++u) {
      float nn = __int_as_float(Ee[u].y);
      EFMA(nn, V[u])
    }
  }
  ((float4*)out)[(size_t)widx * 32 + c4] = acc;
}

// ---------------- Layer-0: aggregate projected embeddings (bf16 ztw) — 8-deep ----------------

__global__ __launch_bounds__(256) void k_agg_emb(const unsigned short* __restrict__ ZTW,
    const int* __restrict__ z, const int2* __restrict__ elist, const int* __restrict__ cntp,
    const float* __restrict__ dinv, const float* __restrict__ bias,
    unsigned short* __restrict__ out, int n) {
  int wid = (blockIdx.x * 256 + threadIdx.x) >> 5;    // one node per 32-lane half
  if (wid >= n) return;
  int c4 = threadIdx.x & 31;
  const ushort4* zt4 = (const ushort4*)ZTW;           // row = 32 ushort4 (256B)
  int m = cntp[wid];
  const int2* ep = elist + (size_t)wid * CAP;
  float dc = dinv[wid];
  float d2 = dc * dc;
  ushort4 s = zt4[(size_t)z[wid] * 32 + c4];
  float4 acc = make_float4(d2 * b2f(s.x), d2 * b2f(s.y), d2 * b2f(s.z), d2 * b2f(s.w));
  for (int j0 = 0; j0 < m; j0 += 8) {
    int2 Ee[8];
    #pragma unroll
    for (int u = 0; u < 8; ++u) Ee[u] = ep[j0 + u];
    ushort4 V[8];
    #pragma unroll
    for (int u = 0; u < 8; ++u) V[u] = zt4[(size_t)((unsigned)Ee[u].x >> RSHIFT) * 32 + c4];
    #pragma unroll
    for (int u = 0; u < 8; ++u) {
      float nn = __int_as_float(Ee[u].y);
      acc.x = fmaf(nn, b2f(V[u].x), acc.x);
      acc.y = fmaf(nn, b2f(V[u].y), acc.y);
      acc.z = fmaf(nn, b2f(V[u].z), acc.z);
      acc.w = fmaf(nn, b2f(V[u].w), acc.w);
    }
  }
  float4 bb = ((const float4*)bias)[c4];
  ushort4 o = make_ushort4(f2b(fmaxf(acc.x + bb.x, 0.f)),
                           f2b(fmaxf(acc.y + bb.y, 0.f)),
                           f2b(fmaxf(acc.z + bb.z, 0.f)),
                           f2b(fmaxf(acc.w + bb.w, 0.f)));
  ((ushort4*)out)[(size_t)wid * 32 + c4] = o;
}

// ---------------- Head (y rows already ordered: 2g, 2g+1) ----------------

__global__ __launch_bounds__(128) void k_head_y(const float* __restrict__ Y,
    const float* __restrict__ W1, const float* __restrict__ b1,
    const float* __restrict__ W2, const float* __restrict__ b2,
    float* __restrict__ out, int G) {
  int g = blockIdx.x, t = threadIdx.x;
  __shared__ float hs[H];
  hs[t] = Y[(size_t)(2 * g) * H + t] * Y[(size_t)(2 * g + 1) * H + t];
  __syncthreads();
  float a = b1[t];
  #pragma unroll 8
  for (int k = 0; k < H; ++k) a = fmaf(hs[k], W1[k * H + t], a);
  a = fmaxf(a, 0.f);
  a *= W2[t];
  for (int off = 32; off > 0; off >>= 1) a += __shfl_down(a, off);
  __shared__ float wsum[2];
  if ((t & 63) == 0) wsum[t >> 6] = a;
  __syncthreads();
  if (t == 0) out[g] = wsum[0] + wsum[1] + b2[0];
}

// ---------------- launch ----------------

extern "C" void kernel_launch(void* const* d_in, const int* in_sizes, int n_in,
                              void* d_out, int out_size, void* d_ws, size_t ws_size,
                              hipStream_t stream) {
  const int* z     = (const int*)d_in[0];
  const int* eidx  = (const int*)d_in[1];
  const int* batch = (const int*)d_in[2];
  const float* ew  = (const float*)d_in[3];
  const float* ztab= (const float*)d_in[4];
  const float *W0, *W1, *W2, *b0, *b1, *b2, *l1W, *l1b, *l2W, *l2b;
  if (n_in >= 15) {
    W0 = (const float*)d_in[5];  W1 = (const float*)d_in[6];  W2 = (const float*)d_in[7];
    b0 = (const float*)d_in[8];  b1 = (const float*)d_in[9];  b2 = (const float*)d_in[10];
    l1W = (const float*)d_in[11]; l1b = (const float*)d_in[12];
    l2W = (const float*)d_in[13]; l2b = (const float*)d_in[14];
  } else {
    const float* Wss = (const float*)d_in[5];
    W0 = Wss; W1 = Wss + H * H; W2 = Wss + 2 * H * H;
    const float* bs = (const float*)d_in[6];
    b0 = bs; b1 = bs + H; b2 = bs + 2 * H;
    l1W = (const float*)d_in[7]; l1b = (const float*)d_in[8];
    l2W = (const float*)d_in[9]; l2b = (const float*)d_in[10];
  }
  int N = in_sizes[0];
  int E = in_sizes[3];
  int ZTOT = in_sizes[4];      // MAXZ * H
  int MAXZ = ZTOT / H;
  int G = out_size;
  float* fout = (float*)d_out;
  int NC = 2 * G;              // center nodes (pairs)
  int MAXS = NC * (CAP + 1);   // worst-case |S2|
  int NB = (N + BW - 1) >> BSH;  // sort buckets (<=1024)

  size_t woff = 0;
  auto alloc = [&](size_t bytes) {
    void* p = (char*)d_ws + woff;
    woff += (bytes + 255) & ~(size_t)255;
    return p;
  };
  unsigned short* h1b   = (unsigned short*)alloc((size_t)N * H * 2);  // h1 bf16
  unsigned short* xwb   = (unsigned short*)alloc((size_t)N * H * 2);  // h1 @ W1 bf16
  float*          bufB  = (float*)alloc((size_t)N * H * 4);           // h2 (S2 rows)
  unsigned int*   bitmap= (unsigned int*)alloc(((size_t)N + 31) / 32 * 4);
  int*            scount= (int*)alloc(4);
  int*            gcur  = (int*)alloc((size_t)NB * 4);                // contiguous w/ bitmap: one memset
  float*          dinv  = (float*)alloc((size_t)N * 4);
  int*            cnt   = (int*)alloc((size_t)N * 4);
  int*            cntp  = (int*)alloc((size_t)N * 4);
  unsigned short* ztw   = (unsigned short*)alloc((size_t)ZTOT * 2);   // ztab @ W0, bf16
  unsigned short* whl   = (unsigned short*)alloc((size_t)2 * H * H * 2); // W1^T hi/lo bf16
  int*            clist = (int*)alloc((size_t)NC * 4);
  int*            slist = (int*)alloc((size_t)MAXS * 4);
  float*          agg2  = (float*)alloc((size_t)NC * H * 4);
  float*          ybuf  = (float*)alloc((size_t)NC * H * 4);
  u64*            binned= (u64*)alloc((size_t)NB * BCAP * 8);
  int2*           elist = (int2*)alloc((size_t)N * CAP * 8);

  const int* erow = eidx;
  const int* ecol = eidx + E;

  // zero bitmap + scount + gcur in one shot (contiguous allocs)
  size_t zlen = ((((size_t)N + 31) / 32 * 4 + 255) & ~(size_t)255) + 256
              + (((size_t)NB * 4 + 255) & ~(size_t)255);
  hipMemsetAsync(bitmap, 0, zlen, stream);

  int nb = (N + 255) / 256;
  int hgrid = (N + 7) / 8;        // half-per-node kernels

  k_binA<<<(E + EPB - 1) / EPB, 512, 0, stream>>>(erow, ecol, ew, gcur, binned, E, NB);
  k_binB<<<NB, 512, 0, stream>>>(gcur, binned, cnt, dinv, N);
  k_binPack<<<NB, 512, 0, stream>>>(gcur, binned, cntp, dinv, z, elist, N);
  // project z-table through W0 once (1000 rows), bf16 out
  dim3 zgrid((MAXZ + GBM - 1) / GBM, H / GBN);
  k_gemm<<<zgrid, 256, 0, stream>>>(ztab, W0, ztw, MAXZ, nullptr, 0, 1);
  k_wprep<<<(H * H + 255) / 256, 256, 0, stream>>>(W1, whl);
  k_mark<<<(NC + 3) / 4, 256, 0, stream>>>(batch, N, clist, elist, cnt, bitmap, NC);
  k_compact<<<nb, 256, 0, stream>>>(bitmap, slist, scount, N);

  // layer 0: h1 = relu(Agg(ztw[z]) + b0) -> bf16   (one node per 32-lane half)
  k_agg_emb<<<hgrid, 256, 0, stream>>>(ztw, z, elist, cntp, dinv, b0, h1b, N);
  // layer 1: MFMA GEMM (persistent blocks, bf16 X, LDS-staged hi/lo W1) -> bf16; aggregate ONLY S2 nodes
  k_gemm_mfma<<<MFMA_GRID, 256, 0, stream>>>(h1b, whl, xwb, N);
  k_aggb_list<<<(MAXS + 7) / 8, 256, 0, stream>>>(xwb, elist, cntp, dinv, b1, bufB, slist, scount, 1);
  // layer 2 (aggregate-first): t = A.h2 at 1000 centers; y = t @ W2 + b2
  k_agg_last<<<(NC + 7) / 8, 256, 0, stream>>>(bufB, elist, cntp, dinv, clist, agg2, NC);
  dim3 ygrid((NC + GBM - 1) / GBM, H / GBN);
  k_gemm<<<ygrid, 256, 0, stream>>>(agg2, W2, ybuf, NC, b2, 0, 0);

  k_head_y<<<G, 128, 0, stream>>>(ybuf, l1W, l1b, l2W, l2b, fout, G);
}